// Round 1
// baseline (3135.407 us; speedup 1.0000x reference)
//
#include <hip/hip_runtime.h>
#include <math.h>

#define NPTS   8192
#define INCH   1024
#define FDIM   128
#define KNN    10

// ---------------------------------------------------------------------------
// sq[i] = sum_d x[i][d]^2   (one wave per row)
// ---------------------------------------------------------------------------
__global__ __launch_bounds__(256) void sq_kernel(const float* __restrict__ x,
                                                 float* __restrict__ sq) {
    int wave = threadIdx.x >> 6;
    int lane = threadIdx.x & 63;
    int row  = blockIdx.x * 4 + wave;
    const float4* xr = (const float4*)(x + (size_t)row * INCH);
    float s = 0.f;
    #pragma unroll
    for (int i = 0; i < 4; ++i) {
        float4 v = xr[lane + i * 64];
        s += v.x * v.x + v.y * v.y + v.z * v.z + v.w * v.w;
    }
    #pragma unroll
    for (int o = 32; o; o >>= 1) s += __shfl_xor(s, o);
    if (lane == 0) sq[row] = s;
}

// ---------------------------------------------------------------------------
// Distance chunk: D[(i-r0)][j] = sq[i] + sq[j] - 2*dot(x_i, x_j)
// 128x128 tile per block, 256 threads, 8x8 per thread, BK=16.
// ---------------------------------------------------------------------------
__global__ __launch_bounds__(256) void dist_kernel(const float* __restrict__ x,
                                                   const float* __restrict__ sq,
                                                   float* __restrict__ D,
                                                   int r0) {
    __shared__ float As[16][128];
    __shared__ float Bs[16][128];
    int tid = threadIdx.x;
    int tx = tid & 15, ty = tid >> 4;
    int rowBase = r0 + blockIdx.y * 128;
    int colBase = blockIdx.x * 128;

    float acc[8][8];
    #pragma unroll
    for (int i = 0; i < 8; ++i)
        #pragma unroll
        for (int j = 0; j < 8; ++j) acc[i][j] = 0.f;

    int lr = tid >> 1;          // 0..127
    int lk = (tid & 1) * 8;     // 0 or 8
    const float* Arow = x + (size_t)(rowBase + lr) * INCH + lk;
    const float* Brow = x + (size_t)(colBase + lr) * INCH + lk;

    for (int k0 = 0; k0 < INCH; k0 += 16) {
        float4 a0 = *(const float4*)(Arow + k0);
        float4 a1 = *(const float4*)(Arow + k0 + 4);
        float4 b0 = *(const float4*)(Brow + k0);
        float4 b1 = *(const float4*)(Brow + k0 + 4);
        __syncthreads();
        As[lk + 0][lr] = a0.x; As[lk + 1][lr] = a0.y;
        As[lk + 2][lr] = a0.z; As[lk + 3][lr] = a0.w;
        As[lk + 4][lr] = a1.x; As[lk + 5][lr] = a1.y;
        As[lk + 6][lr] = a1.z; As[lk + 7][lr] = a1.w;
        Bs[lk + 0][lr] = b0.x; Bs[lk + 1][lr] = b0.y;
        Bs[lk + 2][lr] = b0.z; Bs[lk + 3][lr] = b0.w;
        Bs[lk + 4][lr] = b1.x; Bs[lk + 5][lr] = b1.y;
        Bs[lk + 6][lr] = b1.z; Bs[lk + 7][lr] = b1.w;
        __syncthreads();
        #pragma unroll
        for (int k = 0; k < 16; ++k) {
            float4 av0 = *(const float4*)&As[k][ty * 8];
            float4 av1 = *(const float4*)&As[k][ty * 8 + 4];
            float4 bv0 = *(const float4*)&Bs[k][tx * 8];
            float4 bv1 = *(const float4*)&Bs[k][tx * 8 + 4];
            float ar[8] = {av0.x, av0.y, av0.z, av0.w, av1.x, av1.y, av1.z, av1.w};
            float br[8] = {bv0.x, bv0.y, bv0.z, bv0.w, bv1.x, bv1.y, bv1.z, bv1.w};
            #pragma unroll
            for (int i = 0; i < 8; ++i)
                #pragma unroll
                for (int j = 0; j < 8; ++j) acc[i][j] += ar[i] * br[j];
        }
    }

    float sqa[8], sqb[8];
    #pragma unroll
    for (int i = 0; i < 8; ++i) sqa[i] = sq[rowBase + ty * 8 + i];
    #pragma unroll
    for (int j = 0; j < 8; ++j) sqb[j] = sq[colBase + tx * 8 + j];

    #pragma unroll
    for (int i = 0; i < 8; ++i) {
        float4 o0, o1;
        o0.x = sqa[i] + sqb[0] - 2.f * acc[i][0];
        o0.y = sqa[i] + sqb[1] - 2.f * acc[i][1];
        o0.z = sqa[i] + sqb[2] - 2.f * acc[i][2];
        o0.w = sqa[i] + sqb[3] - 2.f * acc[i][3];
        o1.x = sqa[i] + sqb[4] - 2.f * acc[i][4];
        o1.y = sqa[i] + sqb[5] - 2.f * acc[i][5];
        o1.z = sqa[i] + sqb[6] - 2.f * acc[i][6];
        o1.w = sqa[i] + sqb[7] - 2.f * acc[i][7];
        size_t o = (size_t)(rowBase + ty * 8 + i - r0) * NPTS + colBase + tx * 8;
        *(float4*)(D + o)     = o0;
        *(float4*)(D + o + 4) = o1;
    }
}

// ---------------------------------------------------------------------------
// Top-10 per row. key = (sortable(dist) << 32) | col ; 10 smallest keys.
// One block (256 threads) per row; per-thread sorted top-10, then block merge.
// ---------------------------------------------------------------------------
__global__ __launch_bounds__(256) void topk_kernel(const float* __restrict__ D,
                                                   int* __restrict__ nn,
                                                   int r0) {
    const float* dr = D + (size_t)blockIdx.x * NPTS;
    int tid = threadIdx.x;
    unsigned long long kv[10];
    #pragma unroll
    for (int p = 0; p < 10; ++p) kv[p] = ~0ull;

    for (int j = tid; j < NPTS; j += 256) {
        float d = dr[j];
        unsigned u = __float_as_uint(d);
        u = (u & 0x80000000u) ? ~u : (u | 0x80000000u);
        unsigned long long key = ((unsigned long long)u << 32) | (unsigned)j;
        if (key < kv[9]) {
            unsigned long long cur = key;
            #pragma unroll
            for (int p = 0; p < 10; ++p) {
                unsigned long long lo = kv[p] < cur ? kv[p] : cur;
                unsigned long long hi = kv[p] < cur ? cur : kv[p];
                kv[p] = lo; cur = hi;
            }
        }
    }

    __shared__ unsigned long long sm4[4];
    __shared__ unsigned long long smWin;
    int lane = tid & 63, wid = tid >> 6;

    for (int r = 0; r < KNN; ++r) {
        unsigned long long h = kv[0];
        #pragma unroll
        for (int o = 32; o; o >>= 1) {
            unsigned long long t = __shfl_xor(h, o);
            h = t < h ? t : h;
        }
        if (lane == 0) sm4[wid] = h;
        __syncthreads();
        if (tid == 0) {
            unsigned long long m = sm4[0];
            #pragma unroll
            for (int i = 1; i < 4; ++i) m = sm4[i] < m ? sm4[i] : m;
            smWin = m;
        }
        __syncthreads();
        unsigned long long m = smWin;
        if (kv[0] == m) {
            #pragma unroll
            for (int p = 0; p < 9; ++p) kv[p] = kv[p + 1];
            kv[9] = ~0ull;
        }
        if (tid == 0)
            nn[(size_t)(r0 + blockIdx.x) * KNN + r] = (int)(m & 0xffffffffu);
        __syncthreads();
    }
}

// ---------------------------------------------------------------------------
// CSR build: Dv counts, prefix scan, fill
// ---------------------------------------------------------------------------
__global__ void count_kernel(const int* __restrict__ nn, int* __restrict__ Dv) {
    int t = blockIdx.x * 256 + threadIdx.x;
    if (t < NPTS * KNN) atomicAdd(&Dv[nn[t]], 1);
}

__global__ __launch_bounds__(256) void scan_kernel(const int* __restrict__ Dv,
                                                   int* __restrict__ off,
                                                   int* __restrict__ cursor) {
    __shared__ int part[256];
    int tid = threadIdx.x;
    int base = tid * 32;
    int loc[32];
    int s = 0;
    #pragma unroll
    for (int i = 0; i < 32; ++i) { loc[i] = s; s += Dv[base + i]; }
    part[tid] = s;
    __syncthreads();
    for (int st = 1; st < 256; st <<= 1) {
        int v = (tid >= st) ? part[tid - st] : 0;
        __syncthreads();
        part[tid] += v;
        __syncthreads();
    }
    int pre = (tid > 0) ? part[tid - 1] : 0;
    #pragma unroll
    for (int i = 0; i < 32; ++i) {
        int o = pre + loc[i];
        off[base + i] = o;
        cursor[base + i] = o;
    }
}

__global__ void fill_kernel(const int* __restrict__ nn, int* __restrict__ cursor,
                            int* __restrict__ csr_list) {
    int t = blockIdx.x * 256 + threadIdx.x;
    if (t < NPTS * KNN) {
        int v = nn[t];
        int pos = atomicAdd(&cursor[v], 1);
        csr_list[pos] = t / KNN;   // hyperedge id
    }
}

// ---------------------------------------------------------------------------
// C[M x 128] = A[M x Kdim] @ B[Kdim x 128], 64x128 tile, 4x8 per thread
// ---------------------------------------------------------------------------
__global__ __launch_bounds__(256) void gemm_n128_kernel(const float* __restrict__ A,
                                                        const float* __restrict__ Bm,
                                                        float* __restrict__ C,
                                                        int Kdim) {
    __shared__ float As[16][64];
    __shared__ float Bs[16][128];
    int tid = threadIdx.x;
    int tx = tid & 15, ty = tid >> 4;
    int rowBase = blockIdx.x * 64;
    float acc[4][8];
    #pragma unroll
    for (int i = 0; i < 4; ++i)
        #pragma unroll
        for (int j = 0; j < 8; ++j) acc[i][j] = 0.f;

    int lr = tid >> 2, lk = (tid & 3) * 4;   // A: 64 rows x 16 k
    int bk = tid >> 4, bc = (tid & 15) * 8;  // B: 16 k x 128 cols

    for (int k0 = 0; k0 < Kdim; k0 += 16) {
        float4 av  = *(const float4*)(A + (size_t)(rowBase + lr) * Kdim + k0 + lk);
        float4 bv0 = *(const float4*)(Bm + (size_t)(k0 + bk) * FDIM + bc);
        float4 bv1 = *(const float4*)(Bm + (size_t)(k0 + bk) * FDIM + bc + 4);
        __syncthreads();
        As[lk + 0][lr] = av.x; As[lk + 1][lr] = av.y;
        As[lk + 2][lr] = av.z; As[lk + 3][lr] = av.w;
        *(float4*)&Bs[bk][bc]     = bv0;
        *(float4*)&Bs[bk][bc + 4] = bv1;
        __syncthreads();
        #pragma unroll
        for (int k = 0; k < 16; ++k) {
            float4 a  = *(const float4*)&As[k][ty * 4];
            float4 c0 = *(const float4*)&Bs[k][tx * 8];
            float4 c1 = *(const float4*)&Bs[k][tx * 8 + 4];
            float ar[4] = {a.x, a.y, a.z, a.w};
            float br[8] = {c0.x, c0.y, c0.z, c0.w, c1.x, c1.y, c1.z, c1.w};
            #pragma unroll
            for (int i = 0; i < 4; ++i)
                #pragma unroll
                for (int j = 0; j < 8; ++j) acc[i][j] += ar[i] * br[j];
        }
    }
    int row = rowBase + ty * 4;
    int col = tx * 8;
    #pragma unroll
    for (int i = 0; i < 4; ++i) {
        float4 o0 = {acc[i][0], acc[i][1], acc[i][2], acc[i][3]};
        float4 o1 = {acc[i][4], acc[i][5], acc[i][6], acc[i][7]};
        *(float4*)(C + (size_t)(row + i) * FDIM + col)     = o0;
        *(float4*)(C + (size_t)(row + i) * FDIM + col + 4) = o1;
    }
}

// ---------------------------------------------------------------------------
// edge_ft[e][c] = mean_{k} t[nn[e][k]][c]   (De == KNN exactly)
// ---------------------------------------------------------------------------
__global__ __launch_bounds__(256) void edge_kernel(const float* __restrict__ t,
                                                   const int* __restrict__ nn,
                                                   float* __restrict__ e) {
    int eid = blockIdx.x * 2 + (threadIdx.x >> 7);
    int c = threadIdx.x & 127;
    const int* nnr = nn + (size_t)eid * KNN;
    float s = 0.f;
    #pragma unroll
    for (int k = 0; k < KNN; ++k)
        s += t[(size_t)nnr[k] * FDIM + c];
    e[(size_t)eid * FDIM + c] = s * (1.f / (float)KNN);
}

// ---------------------------------------------------------------------------
// node_ft[v][c] = (sum_{e in csr(v)} e[e][c]) / max(Dv,1) + bias[c], leaky
// ---------------------------------------------------------------------------
__global__ __launch_bounds__(256) void node_kernel(const float* __restrict__ e,
                                                   const int* __restrict__ csr_off,
                                                   const int* __restrict__ Dv,
                                                   const int* __restrict__ csr_list,
                                                   const float* __restrict__ bias,
                                                   float* __restrict__ out) {
    int v = blockIdx.x * 2 + (threadIdx.x >> 7);
    int c = threadIdx.x & 127;
    int beg = csr_off[v];
    int cnt = Dv[v];
    float s = 0.f;
    for (int k = 0; k < cnt; ++k)
        s += e[(size_t)csr_list[beg + k] * FDIM + c];
    int dn = cnt > 1 ? cnt : 1;
    s = s / (float)dn + bias[c];
    s = (s >= 0.f) ? s : 0.01f * s;
    out[(size_t)v * FDIM + c] = s;
}

// ---------------------------------------------------------------------------
// pooling partials: part[128][128]; block b reduces rows b*128..b*128+127
// ---------------------------------------------------------------------------
__global__ __launch_bounds__(256) void pool_kernel(const float* __restrict__ feats,
                                                   float* __restrict__ part) {
    int c = threadIdx.x & 127;
    int half = threadIdx.x >> 7;
    int r0 = blockIdx.x * 128 + half;
    float s = 0.f;
    for (int i = 0; i < 64; ++i)
        s += feats[(size_t)(r0 + 2 * i) * FDIM + c];
    part[(size_t)(blockIdx.x * 2 + half) * FDIM + c] = s;
}

__global__ __launch_bounds__(128) void final_kernel(const float* __restrict__ part,
                                                    const float* __restrict__ fcw,
                                                    const float* __restrict__ fcb,
                                                    float* __restrict__ out) {
    __shared__ float pool[FDIM];
    int c = threadIdx.x;
    float s = 0.f;
    for (int i = 0; i < 128; ++i)
        s += part[(size_t)i * FDIM + c];
    s *= (1.f / (float)NPTS);
    out[2 + (size_t)NPTS * FDIM + c] = s;   // feats_pool
    pool[c] = s;
    __syncthreads();
    if (c < 2) {
        float z = fcb[c];
        for (int k = 0; k < FDIM; ++k)
            z += pool[k] * fcw[c * FDIM + k];
        out[c] = 1.f / (1.f + expf(-z));
    }
}

// ---------------------------------------------------------------------------
extern "C" void kernel_launch(void* const* d_in, const int* in_sizes, int n_in,
                              void* d_out, int out_size, void* d_ws, size_t ws_size,
                              hipStream_t stream) {
    const float* x   = (const float*)d_in[0];
    const float* th0 = (const float*)d_in[1];
    const float* b0  = (const float*)d_in[2];
    const float* th1 = (const float*)d_in[3];
    const float* b1  = (const float*)d_in[4];
    const float* fcw = (const float*)d_in[5];
    const float* fcb = (const float*)d_in[6];
    float* out = (float*)d_out;

    char* w = (char*)d_ws;
    size_t off = 0;
    auto alloc = [&](size_t bytes) -> void* {
        void* p = w + off;
        off = (off + bytes + 255) & ~(size_t)255;
        return p;
    };
    float* sq       = (float*)alloc(NPTS * 4);
    int*   nn       = (int*)  alloc(NPTS * KNN * 4);
    int*   Dv       = (int*)  alloc(NPTS * 4);
    int*   csr_off  = (int*)  alloc(NPTS * 4);
    int*   cursor   = (int*)  alloc(NPTS * 4);
    int*   csr_list = (int*)  alloc(NPTS * KNN * 4);
    float* tbuf     = (float*)alloc((size_t)NPTS * FDIM * 4);
    float* ebuf     = (float*)alloc((size_t)NPTS * FDIM * 4);
    float* hbuf     = (float*)alloc((size_t)NPTS * FDIM * 4);
    float* part     = (float*)alloc(128 * FDIM * 4);

    size_t rem = ws_size > off ? ws_size - off : 0;
    long long chMax = (long long)(rem / ((size_t)NPTS * 4));
    int CH = (int)(chMax > 1024 ? 1024 : chMax);
    CH &= ~127;
    if (CH < 128) CH = 128;   // minimum viable chunk
    float* Dchunk = (float*)(w + off);

    hipMemsetAsync(Dv, 0, NPTS * 4, stream);
    sq_kernel<<<NPTS / 4, 256, 0, stream>>>(x, sq);

    for (int r0 = 0; r0 < NPTS; r0 += CH) {
        int ch = NPTS - r0 < CH ? NPTS - r0 : CH;
        dist_kernel<<<dim3(NPTS / 128, ch / 128), 256, 0, stream>>>(x, sq, Dchunk, r0);
        topk_kernel<<<ch, 256, 0, stream>>>(Dchunk, nn, r0);
    }

    count_kernel<<<(NPTS * KNN + 255) / 256, 256, 0, stream>>>(nn, Dv);
    scan_kernel<<<1, 256, 0, stream>>>(Dv, csr_off, cursor);
    fill_kernel<<<(NPTS * KNN + 255) / 256, 256, 0, stream>>>(nn, cursor, csr_list);

    // layer 0
    gemm_n128_kernel<<<NPTS / 64, 256, 0, stream>>>(x, th0, tbuf, INCH);
    edge_kernel<<<NPTS / 2, 256, 0, stream>>>(tbuf, nn, ebuf);
    node_kernel<<<NPTS / 2, 256, 0, stream>>>(ebuf, csr_off, Dv, csr_list, b0, hbuf);

    // layer 1 -> feats written directly into out+2
    gemm_n128_kernel<<<NPTS / 64, 256, 0, stream>>>(hbuf, th1, tbuf, FDIM);
    edge_kernel<<<NPTS / 2, 256, 0, stream>>>(tbuf, nn, ebuf);
    node_kernel<<<NPTS / 2, 256, 0, stream>>>(ebuf, csr_off, Dv, csr_list, b1, out + 2);

    pool_kernel<<<64, 256, 0, stream>>>(out + 2, part);
    final_kernel<<<1, 128, 0, stream>>>(part, fcw, fcb, out);
}

// Round 2
// 2193.259 us; speedup vs baseline: 1.4296x; 1.4296x over previous
//
#include <hip/hip_runtime.h>
#include <math.h>

#define NPTS   8192
#define INCH   1024
#define FDIM   128
#define KNN    10

// ---------------------------------------------------------------------------
// sq[i] = sum_d x[i][d]^2   (one wave per row)
// ---------------------------------------------------------------------------
__global__ __launch_bounds__(256) void sq_kernel(const float* __restrict__ x,
                                                 float* __restrict__ sq) {
    int wave = threadIdx.x >> 6;
    int lane = threadIdx.x & 63;
    int row  = blockIdx.x * 4 + wave;
    const float4* xr = (const float4*)(x + (size_t)row * INCH);
    float s = 0.f;
    #pragma unroll
    for (int i = 0; i < 4; ++i) {
        float4 v = xr[lane + i * 64];
        s += v.x * v.x + v.y * v.y + v.z * v.z + v.w * v.w;
    }
    #pragma unroll
    for (int o = 32; o; o >>= 1) s += __shfl_xor(s, o);
    if (lane == 0) sq[row] = s;
}

// ---------------------------------------------------------------------------
// Distance chunk: D[(i-r0)][j] = sq[i] + sq[j] - 2*dot(x_i, x_j)
// 128x128 tile per block, 256 threads, 8x8 per thread, BK=16.
// ---------------------------------------------------------------------------
__global__ __launch_bounds__(256) void dist_kernel(const float* __restrict__ x,
                                                   const float* __restrict__ sq,
                                                   float* __restrict__ D,
                                                   int r0) {
    __shared__ float As[16][128];
    __shared__ float Bs[16][128];
    int tid = threadIdx.x;
    int tx = tid & 15, ty = tid >> 4;
    int rowBase = r0 + blockIdx.y * 128;
    int colBase = blockIdx.x * 128;

    float acc[8][8];
    #pragma unroll
    for (int i = 0; i < 8; ++i)
        #pragma unroll
        for (int j = 0; j < 8; ++j) acc[i][j] = 0.f;

    int lr = tid >> 1;          // 0..127
    int lk = (tid & 1) * 8;     // 0 or 8
    const float* Arow = x + (size_t)(rowBase + lr) * INCH + lk;
    const float* Brow = x + (size_t)(colBase + lr) * INCH + lk;

    for (int k0 = 0; k0 < INCH; k0 += 16) {
        float4 a0 = *(const float4*)(Arow + k0);
        float4 a1 = *(const float4*)(Arow + k0 + 4);
        float4 b0 = *(const float4*)(Brow + k0);
        float4 b1 = *(const float4*)(Brow + k0 + 4);
        __syncthreads();
        As[lk + 0][lr] = a0.x; As[lk + 1][lr] = a0.y;
        As[lk + 2][lr] = a0.z; As[lk + 3][lr] = a0.w;
        As[lk + 4][lr] = a1.x; As[lk + 5][lr] = a1.y;
        As[lk + 6][lr] = a1.z; As[lk + 7][lr] = a1.w;
        Bs[lk + 0][lr] = b0.x; Bs[lk + 1][lr] = b0.y;
        Bs[lk + 2][lr] = b0.z; Bs[lk + 3][lr] = b0.w;
        Bs[lk + 4][lr] = b1.x; Bs[lk + 5][lr] = b1.y;
        Bs[lk + 6][lr] = b1.z; Bs[lk + 7][lr] = b1.w;
        __syncthreads();
        #pragma unroll
        for (int k = 0; k < 16; ++k) {
            float4 av0 = *(const float4*)&As[k][ty * 8];
            float4 av1 = *(const float4*)&As[k][ty * 8 + 4];
            float4 bv0 = *(const float4*)&Bs[k][tx * 8];
            float4 bv1 = *(const float4*)&Bs[k][tx * 8 + 4];
            float ar[8] = {av0.x, av0.y, av0.z, av0.w, av1.x, av1.y, av1.z, av1.w};
            float br[8] = {bv0.x, bv0.y, bv0.z, bv0.w, bv1.x, bv1.y, bv1.z, bv1.w};
            #pragma unroll
            for (int i = 0; i < 8; ++i)
                #pragma unroll
                for (int j = 0; j < 8; ++j) acc[i][j] += ar[i] * br[j];
        }
    }

    float sqa[8], sqb[8];
    #pragma unroll
    for (int i = 0; i < 8; ++i) sqa[i] = sq[rowBase + ty * 8 + i];
    #pragma unroll
    for (int j = 0; j < 8; ++j) sqb[j] = sq[colBase + tx * 8 + j];

    #pragma unroll
    for (int i = 0; i < 8; ++i) {
        float4 o0, o1;
        o0.x = sqa[i] + sqb[0] - 2.f * acc[i][0];
        o0.y = sqa[i] + sqb[1] - 2.f * acc[i][1];
        o0.z = sqa[i] + sqb[2] - 2.f * acc[i][2];
        o0.w = sqa[i] + sqb[3] - 2.f * acc[i][3];
        o1.x = sqa[i] + sqb[4] - 2.f * acc[i][4];
        o1.y = sqa[i] + sqb[5] - 2.f * acc[i][5];
        o1.z = sqa[i] + sqb[6] - 2.f * acc[i][6];
        o1.w = sqa[i] + sqb[7] - 2.f * acc[i][7];
        size_t o = (size_t)(rowBase + ty * 8 + i - r0) * NPTS + colBase + tx * 8;
        *(float4*)(D + o)     = o0;
        *(float4*)(D + o + 4) = o1;
    }
}

// ---------------------------------------------------------------------------
// Top-10 per row. key = (sortable(dist) << 32) | col ; 10 smallest keys.
// ---------------------------------------------------------------------------
__global__ __launch_bounds__(256) void topk_kernel(const float* __restrict__ D,
                                                   int* __restrict__ nn,
                                                   int r0) {
    const float* dr = D + (size_t)blockIdx.x * NPTS;
    int tid = threadIdx.x;
    unsigned long long kv[10];
    #pragma unroll
    for (int p = 0; p < 10; ++p) kv[p] = ~0ull;

    for (int j = tid; j < NPTS; j += 256) {
        float d = dr[j];
        unsigned u = __float_as_uint(d);
        u = (u & 0x80000000u) ? ~u : (u | 0x80000000u);
        unsigned long long key = ((unsigned long long)u << 32) | (unsigned)j;
        if (key < kv[9]) {
            unsigned long long cur = key;
            #pragma unroll
            for (int p = 0; p < 10; ++p) {
                unsigned long long lo = kv[p] < cur ? kv[p] : cur;
                unsigned long long hi = kv[p] < cur ? cur : kv[p];
                kv[p] = lo; cur = hi;
            }
        }
    }

    __shared__ unsigned long long sm4[4];
    __shared__ unsigned long long smWin;
    int lane = tid & 63, wid = tid >> 6;

    for (int r = 0; r < KNN; ++r) {
        unsigned long long h = kv[0];
        #pragma unroll
        for (int o = 32; o; o >>= 1) {
            unsigned long long t = __shfl_xor(h, o);
            h = t < h ? t : h;
        }
        if (lane == 0) sm4[wid] = h;
        __syncthreads();
        if (tid == 0) {
            unsigned long long m = sm4[0];
            #pragma unroll
            for (int i = 1; i < 4; ++i) m = sm4[i] < m ? sm4[i] : m;
            smWin = m;
        }
        __syncthreads();
        unsigned long long m = smWin;
        if (kv[0] == m) {
            #pragma unroll
            for (int p = 0; p < 9; ++p) kv[p] = kv[p + 1];
            kv[9] = ~0ull;
        }
        if (tid == 0)
            nn[(size_t)(r0 + blockIdx.x) * KNN + r] = (int)(m & 0xffffffffu);
        __syncthreads();
    }
}

// ---------------------------------------------------------------------------
// Dv counts (node degrees)
// ---------------------------------------------------------------------------
__global__ void count_kernel(const int* __restrict__ nn, int* __restrict__ Dv) {
    int t = blockIdx.x * 256 + threadIdx.x;
    if (t < NPTS * KNN) atomicAdd(&Dv[nn[t]], 1);
}

// ---------------------------------------------------------------------------
// C[M x 128] = A[M x Kdim] @ B[Kdim x 128], 64x128 tile, 4x8 per thread
// ---------------------------------------------------------------------------
__global__ __launch_bounds__(256) void gemm_n128_kernel(const float* __restrict__ A,
                                                        const float* __restrict__ Bm,
                                                        float* __restrict__ C,
                                                        int Kdim) {
    __shared__ float As[16][64];
    __shared__ float Bs[16][128];
    int tid = threadIdx.x;
    int tx = tid & 15, ty = tid >> 4;
    int rowBase = blockIdx.x * 64;
    float acc[4][8];
    #pragma unroll
    for (int i = 0; i < 4; ++i)
        #pragma unroll
        for (int j = 0; j < 8; ++j) acc[i][j] = 0.f;

    int lr = tid >> 2, lk = (tid & 3) * 4;   // A: 64 rows x 16 k
    int bk = tid >> 4, bc = (tid & 15) * 8;  // B: 16 k x 128 cols

    for (int k0 = 0; k0 < Kdim; k0 += 16) {
        float4 av  = *(const float4*)(A + (size_t)(rowBase + lr) * Kdim + k0 + lk);
        float4 bv0 = *(const float4*)(Bm + (size_t)(k0 + bk) * FDIM + bc);
        float4 bv1 = *(const float4*)(Bm + (size_t)(k0 + bk) * FDIM + bc + 4);
        __syncthreads();
        As[lk + 0][lr] = av.x; As[lk + 1][lr] = av.y;
        As[lk + 2][lr] = av.z; As[lk + 3][lr] = av.w;
        *(float4*)&Bs[bk][bc]     = bv0;
        *(float4*)&Bs[bk][bc + 4] = bv1;
        __syncthreads();
        #pragma unroll
        for (int k = 0; k < 16; ++k) {
            float4 a  = *(const float4*)&As[k][ty * 4];
            float4 c0 = *(const float4*)&Bs[k][tx * 8];
            float4 c1 = *(const float4*)&Bs[k][tx * 8 + 4];
            float ar[4] = {a.x, a.y, a.z, a.w};
            float br[8] = {c0.x, c0.y, c0.z, c0.w, c1.x, c1.y, c1.z, c1.w};
            #pragma unroll
            for (int i = 0; i < 4; ++i)
                #pragma unroll
                for (int j = 0; j < 8; ++j) acc[i][j] += ar[i] * br[j];
        }
    }
    int row = rowBase + ty * 4;
    int col = tx * 8;
    #pragma unroll
    for (int i = 0; i < 4; ++i) {
        float4 o0 = {acc[i][0], acc[i][1], acc[i][2], acc[i][3]};
        float4 o1 = {acc[i][4], acc[i][5], acc[i][6], acc[i][7]};
        *(float4*)(C + (size_t)(row + i) * FDIM + col)     = o0;
        *(float4*)(C + (size_t)(row + i) * FDIM + col + 4) = o1;
    }
}

// ---------------------------------------------------------------------------
// edge_ft[e][c] = mean_{k} t[nn[e][k]][c]   (De == KNN exactly)
// ---------------------------------------------------------------------------
__global__ __launch_bounds__(256) void edge_kernel(const float* __restrict__ t,
                                                   const int* __restrict__ nn,
                                                   float* __restrict__ e) {
    int eid = blockIdx.x * 2 + (threadIdx.x >> 7);
    int c = threadIdx.x & 127;
    const int* nnr = nn + (size_t)eid * KNN;
    float s = 0.f;
    #pragma unroll
    for (int k = 0; k < KNN; ++k)
        s += t[(size_t)nnr[k] * FDIM + c];
    e[(size_t)eid * FDIM + c] = s * (1.f / (float)KNN);
}

// ---------------------------------------------------------------------------
// Edge-parallel scatter: for incidence pair t, v=nn[t], e=t/KNN:
//   acc[v][c] += edge_ft[e][c]   (atomic; balanced over pairs)
// ---------------------------------------------------------------------------
__global__ __launch_bounds__(256) void scatter_kernel(const float* __restrict__ e,
                                                      const int* __restrict__ nn,
                                                      float* __restrict__ acc) {
    int t = blockIdx.x * 2 + (threadIdx.x >> 7);   // incidence pair id
    int c = threadIdx.x & 127;
    int v = nn[t];
    int eid = t / KNN;
    float val = e[(size_t)eid * FDIM + c];
    atomicAdd(&acc[(size_t)v * FDIM + c], val);
}

// ---------------------------------------------------------------------------
// node_ft[v][c] = acc[v][c] / max(Dv,1) + bias[c], leaky relu
// ---------------------------------------------------------------------------
__global__ __launch_bounds__(256) void finish_kernel(const float* __restrict__ acc,
                                                     const int* __restrict__ Dv,
                                                     const float* __restrict__ bias,
                                                     float* __restrict__ out) {
    int v = blockIdx.x * 2 + (threadIdx.x >> 7);
    int c = threadIdx.x & 127;
    int cnt = Dv[v];
    float dn = cnt > 1 ? (float)cnt : 1.f;
    float s = acc[(size_t)v * FDIM + c] / dn + bias[c];
    s = (s >= 0.f) ? s : 0.01f * s;
    out[(size_t)v * FDIM + c] = s;
}

// ---------------------------------------------------------------------------
// pooling partials: part[128][128]; block b reduces rows b*128..b*128+127
// ---------------------------------------------------------------------------
__global__ __launch_bounds__(256) void pool_kernel(const float* __restrict__ feats,
                                                   float* __restrict__ part) {
    int c = threadIdx.x & 127;
    int half = threadIdx.x >> 7;
    int r0 = blockIdx.x * 128 + half;
    float s = 0.f;
    for (int i = 0; i < 64; ++i)
        s += feats[(size_t)(r0 + 2 * i) * FDIM + c];
    part[(size_t)(blockIdx.x * 2 + half) * FDIM + c] = s;
}

__global__ __launch_bounds__(128) void final_kernel(const float* __restrict__ part,
                                                    const float* __restrict__ fcw,
                                                    const float* __restrict__ fcb,
                                                    float* __restrict__ out) {
    __shared__ float pool[FDIM];
    int c = threadIdx.x;
    float s = 0.f;
    for (int i = 0; i < 128; ++i)
        s += part[(size_t)i * FDIM + c];
    s *= (1.f / (float)NPTS);
    out[2 + (size_t)NPTS * FDIM + c] = s;   // feats_pool
    pool[c] = s;
    __syncthreads();
    if (c < 2) {
        float z = fcb[c];
        for (int k = 0; k < FDIM; ++k)
            z += pool[k] * fcw[c * FDIM + k];
        out[c] = 1.f / (1.f + expf(-z));
    }
}

// ---------------------------------------------------------------------------
extern "C" void kernel_launch(void* const* d_in, const int* in_sizes, int n_in,
                              void* d_out, int out_size, void* d_ws, size_t ws_size,
                              hipStream_t stream) {
    const float* x   = (const float*)d_in[0];
    const float* th0 = (const float*)d_in[1];
    const float* b0  = (const float*)d_in[2];
    const float* th1 = (const float*)d_in[3];
    const float* b1  = (const float*)d_in[4];
    const float* fcw = (const float*)d_in[5];
    const float* fcb = (const float*)d_in[6];
    float* out = (float*)d_out;

    char* w = (char*)d_ws;
    size_t off = 0;
    auto alloc = [&](size_t bytes) -> void* {
        void* p = w + off;
        off = (off + bytes + 255) & ~(size_t)255;
        return p;
    };
    float* sq    = (float*)alloc(NPTS * 4);
    int*   nn    = (int*)  alloc(NPTS * KNN * 4);
    int*   Dv    = (int*)  alloc(NPTS * 4);
    float* tbuf  = (float*)alloc((size_t)NPTS * FDIM * 4);
    float* ebuf  = (float*)alloc((size_t)NPTS * FDIM * 4);
    float* hbuf  = (float*)alloc((size_t)NPTS * FDIM * 4);
    float* accb  = (float*)alloc((size_t)NPTS * FDIM * 4);
    float* part  = (float*)alloc(128 * FDIM * 4);

    size_t rem = ws_size > off ? ws_size - off : 0;
    long long chMax = (long long)(rem / ((size_t)NPTS * 4));
    int CH = (int)(chMax > 1024 ? 1024 : chMax);
    CH &= ~127;
    if (CH < 128) CH = 128;   // minimum viable chunk
    float* Dchunk = (float*)(w + off);

    hipMemsetAsync(Dv, 0, NPTS * 4, stream);
    sq_kernel<<<NPTS / 4, 256, 0, stream>>>(x, sq);

    for (int r0 = 0; r0 < NPTS; r0 += CH) {
        int ch = NPTS - r0 < CH ? NPTS - r0 : CH;
        dist_kernel<<<dim3(NPTS / 128, ch / 128), 256, 0, stream>>>(x, sq, Dchunk, r0);
        topk_kernel<<<ch, 256, 0, stream>>>(Dchunk, nn, r0);
    }

    count_kernel<<<(NPTS * KNN + 255) / 256, 256, 0, stream>>>(nn, Dv);

    // layer 0
    gemm_n128_kernel<<<NPTS / 64, 256, 0, stream>>>(x, th0, tbuf, INCH);
    edge_kernel<<<NPTS / 2, 256, 0, stream>>>(tbuf, nn, ebuf);
    hipMemsetAsync(accb, 0, (size_t)NPTS * FDIM * 4, stream);
    scatter_kernel<<<NPTS * KNN / 2, 256, 0, stream>>>(ebuf, nn, accb);
    finish_kernel<<<NPTS / 2, 256, 0, stream>>>(accb, Dv, b0, hbuf);

    // layer 1 -> feats written directly into out+2
    gemm_n128_kernel<<<NPTS / 64, 256, 0, stream>>>(hbuf, th1, tbuf, FDIM);
    edge_kernel<<<NPTS / 2, 256, 0, stream>>>(tbuf, nn, ebuf);
    hipMemsetAsync(accb, 0, (size_t)NPTS * FDIM * 4, stream);
    scatter_kernel<<<NPTS * KNN / 2, 256, 0, stream>>>(ebuf, nn, accb);
    finish_kernel<<<NPTS / 2, 256, 0, stream>>>(accb, Dv, b1, out + 2);

    pool_kernel<<<64, 256, 0, stream>>>(out + 2, part);
    final_kernel<<<1, 128, 0, stream>>>(part, fcw, fcb, out);
}